// Round 5
// baseline (565.837 us; speedup 1.0000x reference)
//
#include <hip/hip_runtime.h>

#define DF 64

typedef __attribute__((ext_vector_type(8))) short bf16x8;
typedef __attribute__((ext_vector_type(2))) short v2s;
typedef __attribute__((ext_vector_type(4))) float f32x4;

__device__ __forceinline__ short f2bf(float f) {
    union { float f; unsigned u; } v; v.f = f;
    unsigned u = v.u;
    u += 0x7FFFu + ((u >> 16) & 1u);   // RNE
    return (short)(u >> 16);
}

__device__ __forceinline__ float bf2f(unsigned s) {
    union { unsigned u; float f; } v; v.u = s << 16;
    return v.f;
}

__device__ __forceinline__ bf16x8 cvt8(float4 a, float4 b) {
    bf16x8 r;
    r[0] = f2bf(a.x); r[1] = f2bf(a.y); r[2] = f2bf(a.z); r[3] = f2bf(a.w);
    r[4] = f2bf(b.x); r[5] = f2bf(b.y); r[6] = f2bf(b.z); r[7] = f2bf(b.w);
    return r;
}

// Intra-wave LDS sync: lsH slices are wave-private; lgkmcnt(0) + sched fence
// is sufficient (rule #18). Verified neutral-safe in round 1.
__device__ __forceinline__ void wave_lds_sync() {
    asm volatile("s_waitcnt lgkmcnt(0)" ::: "memory");
    __builtin_amdgcn_sched_barrier(0);
}

// packed bf16x2 atomic add (fallback path only)
__device__ __forceinline__ void pk_add(short* addr, int val) {
#if __has_builtin(__builtin_amdgcn_global_atomic_fadd_v2bf16)
    __builtin_amdgcn_global_atomic_fadd_v2bf16(
        (__attribute__((address_space(1))) v2s*)addr, *(v2s*)&val);
#else
    unsigned* a = (unsigned*)addr;
    unsigned old = *a, assumed;
    do {
        assumed = old;
        float lo = bf2f(assumed & 0xffffu) + bf2f((unsigned)val & 0xffffu);
        float hi = bf2f(assumed >> 16)     + bf2f((unsigned)val >> 16);
        unsigned nv = (unsigned)(unsigned short)f2bf(lo) |
                      ((unsigned)(unsigned short)f2bf(hi) << 16);
        old = atomicCAS(a, assumed, nv);
    } while (old != assumed);
#endif
}

// Transpose + convert the 4 weight matrices to bf16 [n][k] (B^T) once per launch.
__global__ __launch_bounds__(256) void prep_weights(
    const float* __restrict__ w1a, const float* __restrict__ w1b,
    const float* __restrict__ w2a, const float* __restrict__ w2b,
    short* __restrict__ w1aT, short* __restrict__ w1bT,
    short* __restrict__ w2aT, short* __restrict__ w2bT)
{
    int gid = blockIdx.x * 256 + threadIdx.x;   // 24576 total
    if (gid < 8192) {
        int k = gid >> 6, n = gid & 63;
        w1aT[n * 128 + k] = f2bf(w1a[gid]);
    } else if (gid < 12288) {
        int g = gid - 8192; int k = g >> 6, n = g & 63;
        w1bT[n * 64 + k] = f2bf(w1b[g]);
    } else if (gid < 20480) {
        int g = gid - 12288; int k = g >> 6, n = g & 63;
        w2aT[n * 128 + k] = f2bf(w2a[g]);
    } else if (gid < 24576) {
        int g = gid - 20480; int k = g >> 6, n = g & 63;
        w2bT[n * 64 + k] = f2bf(w2b[g]);
    }
}

// ------------------------- CSR (sorted) path ---------------------------------

// Histogram of destination nodes: 800k int atomics (vs 27.2M in fallback path).
__global__ __launch_bounds__(256) void histogram_k(
    const int* __restrict__ ei, int* __restrict__ icounts, int E)
{
    int gid = blockIdx.x * 256 + threadIdx.x;
    if (gid < E) atomicAdd(&icounts[ei[E + gid]], 1);
}

// Exclusive prefix sum over icounts[NN] -> offsets[NN+1] and cursor[NN].
// Single 1024-thread block. Verified correct in round 2.
__global__ __launch_bounds__(1024) void scan_offsets(
    const int* __restrict__ icounts, int* __restrict__ offsets,
    int* __restrict__ cursor, int NN, int E)
{
    __shared__ int part[1024];
    const int t = threadIdx.x;
    const int chunk = (NN + 1023) / 1024;
    const int s = t * chunk;
    const int e = (s + chunk < NN) ? s + chunk : NN;
    int sum = 0;
    for (int i = s; i < e; ++i) sum += icounts[i];
    part[t] = sum;
    __syncthreads();
    for (int off = 1; off < 1024; off <<= 1) {
        int v = part[t];
        int o = (t >= off) ? part[t - off] : 0;
        __syncthreads();
        part[t] = v + o;
        __syncthreads();
    }
    int run = part[t] - sum;   // exclusive prefix of this chunk
    for (int i = s; i < e; ++i) {
        offsets[i] = run;
        cursor[i]  = run;
        run += icounts[i];
    }
    if (t == 0) offsets[NN] = E;
}

// Edge MLP -> destination-sorted rows. 2 tiles (32 edges) per wave, 128-VGPR
// budget (round-4 proven). Placement atomic issued at kernel START so its
// return latency overlaps gathers + both GEMMs; plain coalesced 128-B stores.
__global__ __launch_bounds__(256, 4) void edge_mlp_sorted(
    const float* __restrict__ x, const int* __restrict__ ei,
    const float* __restrict__ ea,
    const short* __restrict__ w1aT, const float* __restrict__ b1a,
    const short* __restrict__ w1bT, const float* __restrict__ b1b,
    short* __restrict__ h_sorted, int* __restrict__ cursor, int E)
{
    __shared__ alignas(16) short lsH[4 * 2 * 16 * 72];   // 18.4 KB, wave-private x2

    const int t = threadIdx.x;
    const int lane = t & 63;
    const int w = t >> 6;
    const int q = lane >> 4;
    const int m = lane & 15;
    const long base = ((long)blockIdx.x * 4 + w) * 32;

    const long e0 = base + m;            // tile 0 edge for this lane
    const long e1 = base + 16 + m;       // tile 1
    const long ec0 = e0 < E ? e0 : (long)(E - 1);
    const long ec1 = e1 < E ? e1 : (long)(E - 1);
    const int row0 = ei[ec0];
    const int row1 = ei[ec1];

    // Placement slot: one returning atomic per edge, issued EARLY (consumed
    // only at the store phase ~both GEMMs later).
    int pos = 0;
    if (lane < 32) {
        long eg = base + lane;
        if (eg < E) pos = atomicAdd(&cursor[ei[E + eg]], 1);
    }

    const float4* xr0 = (const float4*)(x + (long)row0 * DF);
    const float4* er0 = (const float4*)(ea + ec0 * DF);
    const float4* xr1 = (const float4*)(x + (long)row1 * DF);
    const float4* er1 = (const float4*)(ea + ec1 * DF);

    // Issue ALL 16 gather float4s up front — independent, can all be in flight.
    float4 ax0 = xr0[q * 2],     ax1 = xr0[q * 2 + 1];
    float4 ax2 = xr0[8 + q * 2], ax3 = xr0[8 + q * 2 + 1];
    float4 ae0 = er0[q * 2],     ae1 = er0[q * 2 + 1];
    float4 ae2 = er0[8 + q * 2], ae3 = er0[8 + q * 2 + 1];
    float4 bx0 = xr1[q * 2],     bx1 = xr1[q * 2 + 1];
    float4 bx2 = xr1[8 + q * 2], bx3 = xr1[8 + q * 2 + 1];
    float4 be0 = er1[q * 2],     be1 = er1[q * 2 + 1];
    float4 be2 = er1[8 + q * 2], be3 = er1[8 + q * 2 + 1];

    bf16x8 afr0[4], afr1[4];
    afr0[0] = cvt8(ax0, ax1); afr0[1] = cvt8(ax2, ax3);
    afr0[2] = cvt8(ae0, ae1); afr0[3] = cvt8(ae2, ae3);
    afr1[0] = cvt8(bx0, bx1); afr1[1] = cvt8(bx2, bx3);
    afr1[2] = cvt8(be0, be1); afr1[3] = cvt8(be2, be3);

    // --- GEMM1 both tiles: [16 x 128] @ [128 x 64]; weight frag loaded once.
    f32x4 acc0[4], acc1[4];
#pragma unroll
    for (int nt = 0; nt < 4; ++nt) {
        float b = b1a[nt * 16 + m];
        f32x4 v = {b, b, b, b};
        acc0[nt] = v; acc1[nt] = v;
#pragma unroll
        for (int ks = 0; ks < 4; ++ks) {
            bf16x8 wf = *(const bf16x8*)&w1aT[(nt * 16 + m) * 128 + ks * 32 + q * 8];
            acc0[nt] = __builtin_amdgcn_mfma_f32_16x16x32_bf16(afr0[ks], wf, acc0[nt], 0, 0, 0);
            acc1[nt] = __builtin_amdgcn_mfma_f32_16x16x32_bf16(afr1[ks], wf, acc1[nt], 0, 0, 0);
        }
    }

    // --- relu, D-layout -> A-layout via wave-private LDS (2 slices per wave)
    short* hw0 = lsH + w * (2 * 16 * 72);
    short* hw1 = hw0 + 16 * 72;
#pragma unroll
    for (int nt = 0; nt < 4; ++nt)
#pragma unroll
        for (int r = 0; r < 4; ++r) {
            float v0 = acc0[nt][r] > 0.f ? acc0[nt][r] : 0.f;
            float v1 = acc1[nt][r] > 0.f ? acc1[nt][r] : 0.f;
            hw0[(q * 4 + r) * 72 + nt * 16 + m] = f2bf(v0);
            hw1[(q * 4 + r) * 72 + nt * 16 + m] = f2bf(v1);
        }
    wave_lds_sync();

    bf16x8 a20[2], a21[2];
    a20[0] = *(const bf16x8*)&hw0[m * 72 + q * 8];
    a20[1] = *(const bf16x8*)&hw0[m * 72 + 32 + q * 8];
    a21[0] = *(const bf16x8*)&hw1[m * 72 + q * 8];
    a21[1] = *(const bf16x8*)&hw1[m * 72 + 32 + q * 8];

    // --- GEMM2 both tiles: [16 x 64] @ [64 x 64]
    f32x4 acd0[4], acd1[4];
#pragma unroll
    for (int nt = 0; nt < 4; ++nt) {
        float b = b1b[nt * 16 + m];
        f32x4 v = {b, b, b, b};
        acd0[nt] = v; acd1[nt] = v;
#pragma unroll
        for (int ks = 0; ks < 2; ++ks) {
            bf16x8 wf = *(const bf16x8*)&w1bT[(nt * 16 + m) * 64 + ks * 32 + q * 8];
            acd0[nt] = __builtin_amdgcn_mfma_f32_16x16x32_bf16(a20[ks], wf, acd0[nt], 0, 0, 0);
            acd1[nt] = __builtin_amdgcn_mfma_f32_16x16x32_bf16(a21[ks], wf, acd1[nt], 0, 0, 0);
        }
    }
    wave_lds_sync();   // stage-1 LDS fully consumed (intra-wave WAR)

    // --- D-layout -> row-major bf16 in LDS
#pragma unroll
    for (int nt = 0; nt < 4; ++nt)
#pragma unroll
        for (int r = 0; r < 4; ++r) {
            hw0[(q * 4 + r) * 72 + nt * 16 + m] = f2bf(acd0[nt][r]);
            hw1[(q * 4 + r) * 72 + nt * 16 + m] = f2bf(acd1[nt][r]);
        }
    wave_lds_sync();

    // --- sorted stores: 8 lanes cover one 128-B row; pos from lanes 0..31.
    const int* hwi0 = (const int*)hw0;
    const int* hwi1 = (const int*)hw1;
    int* hs = (int*)h_sorted;
#pragma unroll
    for (int i = 0; i < 2; ++i) {
        int r = (lane >> 3) + 8 * i;        // r in 0..7 then 8..15
        int posr0 = __shfl(pos, r);         // tile-0 slot (src lanes 0..15)
        int posr1 = __shfl(pos, 16 + r);    // tile-1 slot (src lanes 16..31)
        if (base + r < E) {
            int4 v = *(const int4*)&hwi0[r * 36 + (lane & 7) * 4];
            *(int4*)&hs[(long)posr0 * 32 + (lane & 7) * 4] = v;
        }
        if (base + 16 + r < E) {
            int4 v = *(const int4*)&hwi1[r * 36 + (lane & 7) * 4];
            *(int4*)&hs[(long)posr1 * 32 + (lane & 7) * 4] = v;
        }
    }
}

// Node MLP, CSR aggregation in f32 with 4-row-unrolled loads (8 in flight).
// 2 tiles (32 nodes) per wave.
__global__ __launch_bounds__(256, 4) void node_mlp_sorted(
    const float* __restrict__ x, const short* __restrict__ h_sorted,
    const int* __restrict__ offsets,
    const short* __restrict__ w2aT, const float* __restrict__ b2a,
    const short* __restrict__ w2bT, const float* __restrict__ b2b,
    float* __restrict__ out, int NN)
{
    __shared__ alignas(16) short lsH[4 * 2 * 16 * 72];

    const int t = threadIdx.x;
    const int lane = t & 63;
    const int w = t >> 6;
    const int q = lane >> 4;
    const int m = lane & 15;
    const long base = ((long)blockIdx.x * 4 + w) * 32;

    const long n0 = base + m;
    const long n1 = base + 16 + m;
    const long nc0 = n0 < NN ? n0 : (long)(NN - 1);
    const long nc1 = n1 < NN ? n1 : (long)(NN - 1);

    const int s0a = offsets[nc0];
    const int cnt0 = offsets[nc0 + 1] - s0a;
    const int s1a = offsets[nc1];
    const int cnt1 = offsets[nc1 + 1] - s1a;
    const float inv0 = 1.f / (float)(cnt0 > 1 ? cnt0 : 1);
    const float inv1 = 1.f / (float)(cnt1 > 1 ? cnt1 : 1);

    // x loads issued before aggregation so they overlap it.
    const float4* xr0 = (const float4*)(x + nc0 * DF);
    const float4* xr1 = (const float4*)(x + nc1 * DF);
    float4 ax0 = xr0[q * 2],     ax1 = xr0[q * 2 + 1];
    float4 ax2 = xr0[8 + q * 2], ax3 = xr0[8 + q * 2 + 1];
    float4 bx0 = xr1[q * 2],     bx1 = xr1[q * 2 + 1];
    float4 bx2 = xr1[8 + q * 2], bx3 = xr1[8 + q * 2 + 1];

    float fa0[8], fa1[8], fb0[8], fb1[8];
#pragma unroll
    for (int i = 0; i < 8; ++i) { fa0[i] = 0.f; fa1[i] = 0.f; fb0[i] = 0.f; fb1[i] = 0.f; }

    // tile 0 aggregation: contiguous rows, 4-way unroll = 8 outstanding loads
    {
        int j = 0;
        for (; j + 4 <= cnt0; j += 4) {
            const short* rp = &h_sorted[(long)(s0a + j) * DF];
            bf16x8 r0a = *(const bf16x8*)&rp[q * 8];
            bf16x8 r0b = *(const bf16x8*)&rp[32 + q * 8];
            bf16x8 r1a = *(const bf16x8*)&rp[64 + q * 8];
            bf16x8 r1b = *(const bf16x8*)&rp[96 + q * 8];
            bf16x8 r2a = *(const bf16x8*)&rp[128 + q * 8];
            bf16x8 r2b = *(const bf16x8*)&rp[160 + q * 8];
            bf16x8 r3a = *(const bf16x8*)&rp[192 + q * 8];
            bf16x8 r3b = *(const bf16x8*)&rp[224 + q * 8];
#pragma unroll
            for (int i = 0; i < 8; ++i) {
                fa0[i] += (bf2f((unsigned short)r0a[i]) + bf2f((unsigned short)r1a[i]))
                        + (bf2f((unsigned short)r2a[i]) + bf2f((unsigned short)r3a[i]));
                fa1[i] += (bf2f((unsigned short)r0b[i]) + bf2f((unsigned short)r1b[i]))
                        + (bf2f((unsigned short)r2b[i]) + bf2f((unsigned short)r3b[i]));
            }
        }
        for (; j < cnt0; ++j) {
            const short* rp = &h_sorted[(long)(s0a + j) * DF];
            bf16x8 ra = *(const bf16x8*)&rp[q * 8];
            bf16x8 rb = *(const bf16x8*)&rp[32 + q * 8];
#pragma unroll
            for (int i = 0; i < 8; ++i) {
                fa0[i] += bf2f((unsigned short)ra[i]);
                fa1[i] += bf2f((unsigned short)rb[i]);
            }
        }
    }
    // tile 1 aggregation
    {
        int j = 0;
        for (; j + 4 <= cnt1; j += 4) {
            const short* rp = &h_sorted[(long)(s1a + j) * DF];
            bf16x8 r0a = *(const bf16x8*)&rp[q * 8];
            bf16x8 r0b = *(const bf16x8*)&rp[32 + q * 8];
            bf16x8 r1a = *(const bf16x8*)&rp[64 + q * 8];
            bf16x8 r1b = *(const bf16x8*)&rp[96 + q * 8];
            bf16x8 r2a = *(const bf16x8*)&rp[128 + q * 8];
            bf16x8 r2b = *(const bf16x8*)&rp[160 + q * 8];
            bf16x8 r3a = *(const bf16x8*)&rp[192 + q * 8];
            bf16x8 r3b = *(const bf16x8*)&rp[224 + q * 8];
#pragma unroll
            for (int i = 0; i < 8; ++i) {
                fb0[i] += (bf2f((unsigned short)r0a[i]) + bf2f((unsigned short)r1a[i]))
                        + (bf2f((unsigned short)r2a[i]) + bf2f((unsigned short)r3a[i]));
                fb1[i] += (bf2f((unsigned short)r0b[i]) + bf2f((unsigned short)r1b[i]))
                        + (bf2f((unsigned short)r2b[i]) + bf2f((unsigned short)r3b[i]));
            }
        }
        for (; j < cnt1; ++j) {
            const short* rp = &h_sorted[(long)(s1a + j) * DF];
            bf16x8 ra = *(const bf16x8*)&rp[q * 8];
            bf16x8 rb = *(const bf16x8*)&rp[32 + q * 8];
#pragma unroll
            for (int i = 0; i < 8; ++i) {
                fb0[i] += bf2f((unsigned short)ra[i]);
                fb1[i] += bf2f((unsigned short)rb[i]);
            }
        }
    }

    bf16x8 afr0[4], afr1[4];
    afr0[0] = cvt8(ax0, ax1); afr0[1] = cvt8(ax2, ax3);
    afr1[0] = cvt8(bx0, bx1); afr1[1] = cvt8(bx2, bx3);
#pragma unroll
    for (int i = 0; i < 8; ++i) {
        afr0[2][i] = f2bf(fa0[i] * inv0);
        afr0[3][i] = f2bf(fa1[i] * inv0);
        afr1[2][i] = f2bf(fb0[i] * inv1);
        afr1[3][i] = f2bf(fb1[i] * inv1);
    }

    f32x4 acc0[4], acc1[4];
#pragma unroll
    for (int nt = 0; nt < 4; ++nt) {
        float b = b2a[nt * 16 + m];
        f32x4 v = {b, b, b, b};
        acc0[nt] = v; acc1[nt] = v;
#pragma unroll
        for (int ks = 0; ks < 4; ++ks) {
            bf16x8 wf = *(const bf16x8*)&w2aT[(nt * 16 + m) * 128 + ks * 32 + q * 8];
            acc0[nt] = __builtin_amdgcn_mfma_f32_16x16x32_bf16(afr0[ks], wf, acc0[nt], 0, 0, 0);
            acc1[nt] = __builtin_amdgcn_mfma_f32_16x16x32_bf16(afr1[ks], wf, acc1[nt], 0, 0, 0);
        }
    }

    short* hw0 = lsH + w * (2 * 16 * 72);
    short* hw1 = hw0 + 16 * 72;
#pragma unroll
    for (int nt = 0; nt < 4; ++nt)
#pragma unroll
        for (int r = 0; r < 4; ++r) {
            float v0 = acc0[nt][r] > 0.f ? acc0[nt][r] : 0.f;
            float v1 = acc1[nt][r] > 0.f ? acc1[nt][r] : 0.f;
            hw0[(q * 4 + r) * 72 + nt * 16 + m] = f2bf(v0);
            hw1[(q * 4 + r) * 72 + nt * 16 + m] = f2bf(v1);
        }
    wave_lds_sync();

    bf16x8 a20[2], a21[2];
    a20[0] = *(const bf16x8*)&hw0[m * 72 + q * 8];
    a20[1] = *(const bf16x8*)&hw0[m * 72 + 32 + q * 8];
    a21[0] = *(const bf16x8*)&hw1[m * 72 + q * 8];
    a21[1] = *(const bf16x8*)&hw1[m * 72 + 32 + q * 8];

    f32x4 acd0[4], acd1[4];
#pragma unroll
    for (int nt = 0; nt < 4; ++nt) {
        float b = b2b[nt * 16 + m];
        f32x4 v = {b, b, b, b};
        acd0[nt] = v; acd1[nt] = v;
#pragma unroll
        for (int ks = 0; ks < 2; ++ks) {
            bf16x8 wf = *(const bf16x8*)&w2bT[(nt * 16 + m) * 64 + ks * 32 + q * 8];
            acd0[nt] = __builtin_amdgcn_mfma_f32_16x16x32_bf16(a20[ks], wf, acd0[nt], 0, 0, 0);
            acd1[nt] = __builtin_amdgcn_mfma_f32_16x16x32_bf16(a21[ks], wf, acd1[nt], 0, 0, 0);
        }
    }

#pragma unroll
    for (int r = 0; r < 4; ++r) {
        long o0 = base + q * 4 + r;
        long o1 = base + 16 + q * 4 + r;
        if (o0 < NN) {
#pragma unroll
            for (int nt = 0; nt < 4; ++nt)
                out[o0 * DF + nt * 16 + m] = acd0[nt][r];
        }
        if (o1 < NN) {
#pragma unroll
            for (int nt = 0; nt < 4; ++nt)
                out[o1 * DF + nt * 16 + m] = acd1[nt][r];
        }
    }
}

// ---------------- fallback (verified 439-µs atomic-scatter path) -------------

__global__ __launch_bounds__(256, 4) void edge_mlp_scatter(
    const float* __restrict__ x, const int* __restrict__ ei,
    const float* __restrict__ ea,
    const short* __restrict__ w1aT, const float* __restrict__ b1a,
    const short* __restrict__ w1bT, const float* __restrict__ b1b,
    short* __restrict__ summedh, float* __restrict__ counts, int E)
{
    __shared__ alignas(16) short lsH[4 * 2 * 16 * 72];

    const int t = threadIdx.x;
    const int lane = t & 63;
    const int w = t >> 6;
    const int q = lane >> 4;
    const int m = lane & 15;
    const long base = ((long)blockIdx.x * 4 + w) * 32;

    const long e0 = base + m;
    const long e1 = base + 16 + m;
    const long ec0 = e0 < E ? e0 : (long)(E - 1);
    const long ec1 = e1 < E ? e1 : (long)(E - 1);
    const int row0 = ei[ec0];
    const int row1 = ei[ec1];

    if (q == 0) {
        if (e0 < E) unsafeAtomicAdd(&counts[ei[E + e0]], 1.0f);
        if (e1 < E) unsafeAtomicAdd(&counts[ei[E + e1]], 1.0f);
    }

    const float4* xr0 = (const float4*)(x + (long)row0 * DF);
    const float4* er0 = (const float4*)(ea + ec0 * DF);
    const float4* xr1 = (const float4*)(x + (long)row1 * DF);
    const float4* er1 = (const float4*)(ea + ec1 * DF);

    float4 ax0 = xr0[q * 2],     ax1 = xr0[q * 2 + 1];
    float4 ax2 = xr0[8 + q * 2], ax3 = xr0[8 + q * 2 + 1];
    float4 ae0 = er0[q * 2],     ae1 = er0[q * 2 + 1];
    float4 ae2 = er0[8 + q * 2], ae3 = er0[8 + q * 2 + 1];
    float4 bx0 = xr1[q * 2],     bx1 = xr1[q * 2 + 1];
    float4 bx2 = xr1[8 + q * 2], bx3 = xr1[8 + q * 2 + 1];
    float4 be0 = er1[q * 2],     be1 = er1[q * 2 + 1];
    float4 be2 = er1[8 + q * 2], be3 = er1[8 + q * 2 + 1];

    bf16x8 afr0[4], afr1[4];
    afr0[0] = cvt8(ax0, ax1); afr0[1] = cvt8(ax2, ax3);
    afr0[2] = cvt8(ae0, ae1); afr0[3] = cvt8(ae2, ae3);
    afr1[0] = cvt8(bx0, bx1); afr1[1] = cvt8(bx2, bx3);
    afr1[2] = cvt8(be0, be1); afr1[3] = cvt8(be2, be3);

    f32x4 acc0[4], acc1[4];
#pragma unroll
    for (int nt = 0; nt < 4; ++nt) {
        float b = b1a[nt * 16 + m];
        f32x4 v = {b, b, b, b};
        acc0[nt] = v; acc1[nt] = v;
#pragma unroll
        for (int ks = 0; ks < 4; ++ks) {
            bf16x8 wf = *(const bf16x8*)&w1aT[(nt * 16 + m) * 128 + ks * 32 + q * 8];
            acc0[nt] = __builtin_amdgcn_mfma_f32_16x16x32_bf16(afr0[ks], wf, acc0[nt], 0, 0, 0);
            acc1[nt] = __builtin_amdgcn_mfma_f32_16x16x32_bf16(afr1[ks], wf, acc1[nt], 0, 0, 0);
        }
    }

    short* hw0 = lsH + w * (2 * 16 * 72);
    short* hw1 = hw0 + 16 * 72;
#pragma unroll
    for (int nt = 0; nt < 4; ++nt)
#pragma unroll
        for (int r = 0; r < 4; ++r) {
            float v0 = acc0[nt][r] > 0.f ? acc0[nt][r] : 0.f;
            float v1 = acc1[nt][r] > 0.f ? acc1[nt][r] : 0.f;
            hw0[(q * 4 + r) * 72 + nt * 16 + m] = f2bf(v0);
            hw1[(q * 4 + r) * 72 + nt * 16 + m] = f2bf(v1);
        }
    wave_lds_sync();

    bf16x8 a20[2], a21[2];
    a20[0] = *(const bf16x8*)&hw0[m * 72 + q * 8];
    a20[1] = *(const bf16x8*)&hw0[m * 72 + 32 + q * 8];
    a21[0] = *(const bf16x8*)&hw1[m * 72 + q * 8];
    a21[1] = *(const bf16x8*)&hw1[m * 72 + 32 + q * 8];

    f32x4 acd0[4], acd1[4];
#pragma unroll
    for (int nt = 0; nt < 4; ++nt) {
        float b = b1b[nt * 16 + m];
        f32x4 v = {b, b, b, b};
        acd0[nt] = v; acd1[nt] = v;
#pragma unroll
        for (int ks = 0; ks < 2; ++ks) {
            bf16x8 wf = *(const bf16x8*)&w1bT[(nt * 16 + m) * 64 + ks * 32 + q * 8];
            acd0[nt] = __builtin_amdgcn_mfma_f32_16x16x32_bf16(a20[ks], wf, acd0[nt], 0, 0, 0);
            acd1[nt] = __builtin_amdgcn_mfma_f32_16x16x32_bf16(a21[ks], wf, acd1[nt], 0, 0, 0);
        }
    }
    wave_lds_sync();

#pragma unroll
    for (int nt = 0; nt < 4; ++nt)
#pragma unroll
        for (int r = 0; r < 4; ++r) {
            hw0[(q * 4 + r) * 72 + nt * 16 + m] = f2bf(acd0[nt][r]);
            hw1[(q * 4 + r) * 72 + nt * 16 + m] = f2bf(acd1[nt][r]);
        }
    wave_lds_sync();

    const int p = lane & 31;
    const int* hwi0 = (const int*)hw0;
    const int* hwi1 = (const int*)hw1;
#pragma unroll
    for (int i = 0; i < 8; ++i) {
        int r2 = (lane >> 5) + 2 * i;
        long eg0 = base + r2;
        long eg1 = base + 16 + r2;
        if (eg0 < E) {
            int dst = ei[E + eg0];
            pk_add(&summedh[(long)dst * DF + 2 * p], hwi0[r2 * 36 + p]);
        }
        if (eg1 < E) {
            int dst = ei[E + eg1];
            pk_add(&summedh[(long)dst * DF + 2 * p], hwi1[r2 * 36 + p]);
        }
    }
}

__global__ __launch_bounds__(256, 4) void node_mlp(
    const float* __restrict__ x, const short* __restrict__ summedh,
    const float* __restrict__ counts,
    const short* __restrict__ w2aT, const float* __restrict__ b2a,
    const short* __restrict__ w2bT, const float* __restrict__ b2b,
    float* __restrict__ out, int NN)
{
    __shared__ alignas(16) short lsH[4 * 2 * 16 * 72];

    const int t = threadIdx.x;
    const int lane = t & 63;
    const int w = t >> 6;
    const int q = lane >> 4;
    const int m = lane & 15;
    const long base = ((long)blockIdx.x * 4 + w) * 32;

    const long n0 = base + m;
    const long n1 = base + 16 + m;
    const long nc0 = n0 < NN ? n0 : (long)(NN - 1);
    const long nc1 = n1 < NN ? n1 : (long)(NN - 1);

    const float4* xr0 = (const float4*)(x + nc0 * DF);
    const float4* xr1 = (const float4*)(x + nc1 * DF);

    float4 ax0 = xr0[q * 2],     ax1 = xr0[q * 2 + 1];
    float4 ax2 = xr0[8 + q * 2], ax3 = xr0[8 + q * 2 + 1];
    float4 bx0 = xr1[q * 2],     bx1 = xr1[q * 2 + 1];
    float4 bx2 = xr1[8 + q * 2], bx3 = xr1[8 + q * 2 + 1];
    bf16x8 s00 = *(const bf16x8*)&summedh[nc0 * DF + q * 8];
    bf16x8 s01 = *(const bf16x8*)&summedh[nc0 * DF + 32 + q * 8];
    bf16x8 s10 = *(const bf16x8*)&summedh[nc1 * DF + q * 8];
    bf16x8 s11 = *(const bf16x8*)&summedh[nc1 * DF + 32 + q * 8];
    float c0 = counts[nc0];
    float c1 = counts[nc1];
    c0 = c0 > 1.f ? c0 : 1.f;
    c1 = c1 > 1.f ? c1 : 1.f;
    const float inv0 = 1.f / c0;
    const float inv1 = 1.f / c1;

    bf16x8 afr0[4], afr1[4];
    afr0[0] = cvt8(ax0, ax1); afr0[1] = cvt8(ax2, ax3);
    afr1[0] = cvt8(bx0, bx1); afr1[1] = cvt8(bx2, bx3);
#pragma unroll
    for (int i = 0; i < 8; ++i) {
        afr0[2][i] = f2bf(bf2f((unsigned short)s00[i]) * inv0);
        afr0[3][i] = f2bf(bf2f((unsigned short)s01[i]) * inv0);
        afr1[2][i] = f2bf(bf2f((unsigned short)s10[i]) * inv1);
        afr1[3][i] = f2bf(bf2f((unsigned short)s11[i]) * inv1);
    }

    f32x4 acc0[4], acc1[4];
#pragma unroll
    for (int nt = 0; nt < 4; ++nt) {
        float b = b2a[nt * 16 + m];
        f32x4 v = {b, b, b, b};
        acc0[nt] = v; acc1[nt] = v;
#pragma unroll
        for (int ks = 0; ks < 4; ++ks) {
            bf16x8 wf = *(const bf16x8*)&w2aT[(nt * 16 + m) * 128 + ks * 32 + q * 8];
            acc0[nt] = __builtin_amdgcn_mfma_f32_16x16x32_bf16(afr0[ks], wf, acc0[nt], 0, 0, 0);
            acc1[nt] = __builtin_amdgcn_mfma_f32_16x16x32_bf16(afr1[ks], wf, acc1[nt], 0, 0, 0);
        }
    }

    short* hw0 = lsH + w * (2 * 16 * 72);
    short* hw1 = hw0 + 16 * 72;
#pragma unroll
    for (int nt = 0; nt < 4; ++nt)
#pragma unroll
        for (int r = 0; r < 4; ++r) {
            float v0 = acc0[nt][r] > 0.f ? acc0[nt][r] : 0.f;
            float v1 = acc1[nt][r] > 0.f ? acc1[nt][r] : 0.f;
            hw0[(q * 4 + r) * 72 + nt * 16 + m] = f2bf(v0);
            hw1[(q * 4 + r) * 72 + nt * 16 + m] = f2bf(v1);
        }
    wave_lds_sync();

    bf16x8 a20[2], a21[2];
    a20[0] = *(const bf16x8*)&hw0[m * 72 + q * 8];
    a20[1] = *(const bf16x8*)&hw0[m * 72 + 32 + q * 8];
    a21[0] = *(const bf16x8*)&hw1[m * 72 + q * 8];
    a21[1] = *(const bf16x8*)&hw1[m * 72 + 32 + q * 8];

    f32x4 acd0[4], acd1[4];
#pragma unroll
    for (int nt = 0; nt < 4; ++nt) {
        float b = b2b[nt * 16 + m];
        f32x4 v = {b, b, b, b};
        acd0[nt] = v; acd1[nt] = v;
#pragma unroll
        for (int ks = 0; ks < 2; ++ks) {
            bf16x8 wf = *(const bf16x8*)&w2bT[(nt * 16 + m) * 64 + ks * 32 + q * 8];
            acd0[nt] = __builtin_amdgcn_mfma_f32_16x16x32_bf16(a20[ks], wf, acd0[nt], 0, 0, 0);
            acd1[nt] = __builtin_amdgcn_mfma_f32_16x16x32_bf16(a21[ks], wf, acd1[nt], 0, 0, 0);
        }
    }

#pragma unroll
    for (int r = 0; r < 4; ++r) {
        long o0 = base + q * 4 + r;
        long o1 = base + 16 + q * 4 + r;
        if (o0 < NN) {
#pragma unroll
            for (int nt = 0; nt < 4; ++nt)
                out[o0 * DF + nt * 16 + m] = acd0[nt][r];
        }
        if (o1 < NN) {
#pragma unroll
            for (int nt = 0; nt < 4; ++nt)
                out[o1 * DF + nt * 16 + m] = acd1[nt][r];
        }
    }
}

// ------------------------------ launcher -------------------------------------

extern "C" void kernel_launch(void* const* d_in, const int* in_sizes, int n_in,
                              void* d_out, int out_size, void* d_ws, size_t ws_size,
                              hipStream_t stream) {
    const float* x   = (const float*)d_in[0];
    const int*   ei  = (const int*)d_in[1];
    const float* ea  = (const float*)d_in[2];
    const float* w1a = (const float*)d_in[5];
    const float* b1a = (const float*)d_in[6];
    const float* w1b = (const float*)d_in[7];
    const float* b1b = (const float*)d_in[8];
    const float* w2a = (const float*)d_in[9];
    const float* b2a = (const float*)d_in[10];
    const float* w2b = (const float*)d_in[11];
    const float* b2b = (const float*)d_in[12];

    const int NN = in_sizes[0] / DF;   // 50000
    const int E  = in_sizes[2] / DF;   // 800000

    char* wsb = (char*)d_ws;
    const size_t need_sorted = 1048576 + (size_t)E * DF * sizeof(short);

    int ewaves = (E + 31) / 32;                      // 32 edges per wave
    int eblocks = (ewaves + 3) / 4;
    int nwaves = (NN + 31) / 32;                     // 32 nodes per wave
    int nblocks = (nwaves + 3) / 4;

    if (ws_size >= need_sorted) {
        // CSR path: no coherence-point scatter atomics (0.8M placement atomics).
        int*   icounts = (int*)wsb;                      // 200 KB
        int*   offsets = (int*)(wsb + 262144);           // 200 KB
        int*   cursor  = (int*)(wsb + 524288);           // 200 KB
        short* w1aT    = (short*)(wsb + 786432);
        short* w1bT    = (short*)(wsb + 802816);
        short* w2aT    = (short*)(wsb + 811008);
        short* w2bT    = (short*)(wsb + 827392);
        short* h_sorted= (short*)(wsb + 1048576);        // 102.4 MB

        hipMemsetAsync(icounts, 0, (size_t)NN * sizeof(int), stream);
        prep_weights<<<96, 256, 0, stream>>>(w1a, w1b, w2a, w2b, w1aT, w1bT, w2aT, w2bT);
        histogram_k<<<(E + 255) / 256, 256, 0, stream>>>(ei, icounts, E);
        scan_offsets<<<1, 1024, 0, stream>>>(icounts, offsets, cursor, NN, E);
        edge_mlp_sorted<<<eblocks, 256, 0, stream>>>(x, ei, ea, w1aT, b1a, w1bT, b1b,
                                                     h_sorted, cursor, E);
        node_mlp_sorted<<<nblocks, 256, 0, stream>>>(x, h_sorted, offsets,
                                                     w2aT, b2a, w2bT, b2b,
                                                     (float*)d_out, NN);
    } else {
        // Fallback: verified 439-µs atomic-scatter path.
        float* counts  = (float*)wsb;
        short* w1aT    = (short*)(wsb + 262144);
        short* w1bT    = (short*)(wsb + 278528);
        short* w2aT    = (short*)(wsb + 286720);
        short* w2bT    = (short*)(wsb + 303104);
        short* summedh = (short*)(wsb + 311296);

        hipMemsetAsync(counts, 0, (size_t)NN * sizeof(float), stream);
        hipMemsetAsync(summedh, 0, (size_t)NN * DF * sizeof(short), stream);
        prep_weights<<<96, 256, 0, stream>>>(w1a, w1b, w2a, w2b, w1aT, w1bT, w2aT, w2bT);
        edge_mlp_scatter<<<eblocks, 256, 0, stream>>>(x, ei, ea, w1aT, b1a, w1bT, b1b,
                                                      summedh, counts, E);
        node_mlp<<<nblocks, 256, 0, stream>>>(x, summedh, counts, w2aT, b2a, w2bT, b2b,
                                              (float*)d_out, NN);
    }
}

// Round 6
// 400.413 us; speedup vs baseline: 1.4131x; 1.4131x over previous
//
#include <hip/hip_runtime.h>

#define DF 64

typedef __attribute__((ext_vector_type(8))) short bf16x8;
typedef __attribute__((ext_vector_type(2))) short v2s;
typedef __attribute__((ext_vector_type(4))) float f32x4;

__device__ __forceinline__ short f2bf(float f) {
    union { float f; unsigned u; } v; v.f = f;
    unsigned u = v.u;
    u += 0x7FFFu + ((u >> 16) & 1u);   // RNE
    return (short)(u >> 16);
}

__device__ __forceinline__ float bf2f(unsigned s) {
    union { unsigned u; float f; } v; v.u = s << 16;
    return v.f;
}

__device__ __forceinline__ bf16x8 cvt8(float4 a, float4 b) {
    bf16x8 r;
    r[0] = f2bf(a.x); r[1] = f2bf(a.y); r[2] = f2bf(a.z); r[3] = f2bf(a.w);
    r[4] = f2bf(b.x); r[5] = f2bf(b.y); r[6] = f2bf(b.z); r[7] = f2bf(b.w);
    return r;
}

// Intra-wave LDS sync (rule #18). sched_barrier(0) also pins the software
// pipeline: prefetch loads issued before the first fence cannot sink below it.
__device__ __forceinline__ void wave_lds_sync() {
    asm volatile("s_waitcnt lgkmcnt(0)" ::: "memory");
    __builtin_amdgcn_sched_barrier(0);
}

// packed bf16x2 atomic add (fire-and-forget)
__device__ __forceinline__ void pk_add(short* addr, int val) {
#if __has_builtin(__builtin_amdgcn_global_atomic_fadd_v2bf16)
    __builtin_amdgcn_global_atomic_fadd_v2bf16(
        (__attribute__((address_space(1))) v2s*)addr, *(v2s*)&val);
#else
    unsigned* a = (unsigned*)addr;
    unsigned old = *a, assumed;
    do {
        assumed = old;
        float lo = bf2f(assumed & 0xffffu) + bf2f((unsigned)val & 0xffffu);
        float hi = bf2f(assumed >> 16)     + bf2f((unsigned)val >> 16);
        unsigned nv = (unsigned)(unsigned short)f2bf(lo) |
                      ((unsigned)(unsigned short)f2bf(hi) << 16);
        old = atomicCAS(a, assumed, nv);
    } while (old != assumed);
#endif
}

// Transpose + convert the 4 weight matrices to bf16 [n][k] (B^T) once per launch.
__global__ __launch_bounds__(256) void prep_weights(
    const float* __restrict__ w1a, const float* __restrict__ w1b,
    const float* __restrict__ w2a, const float* __restrict__ w2b,
    short* __restrict__ w1aT, short* __restrict__ w1bT,
    short* __restrict__ w2aT, short* __restrict__ w2bT)
{
    int gid = blockIdx.x * 256 + threadIdx.x;   // 24576 total
    if (gid < 8192) {
        int k = gid >> 6, n = gid & 63;
        w1aT[n * 128 + k] = f2bf(w1a[gid]);
    } else if (gid < 12288) {
        int g = gid - 8192; int k = g >> 6, n = g & 63;
        w1bT[n * 64 + k] = f2bf(w1b[g]);
    } else if (gid < 20480) {
        int g = gid - 12288; int k = g >> 6, n = g & 63;
        w2aT[n * 128 + k] = f2bf(w2a[g]);
    } else if (gid < 24576) {
        int g = gid - 20480; int k = g >> 6, n = g & 63;
        w2bT[n * 64 + k] = f2bf(w2b[g]);
    }
}

// x -> bf16 (RNE, identical values to the previous per-edge conversion).
__global__ __launch_bounds__(256) void conv_x(
    const float* __restrict__ x, short* __restrict__ xbf, int n8)
{
    int gid = blockIdx.x * 256 + threadIdx.x;
    if (gid < n8) {
        const float4* p = (const float4*)x + (long)gid * 2;
        float4 a = p[0], b = p[1];
        ((bf16x8*)xbf)[gid] = cvt8(a, b);
    }
}

// Edge MLP + packed-bf16 scatter-add. Persistent grid-stride waves with a
// 1-deep software pipeline: tile i+1's gathers and tile i+2's index rows are
// in flight while tile i computes. Weights live in XOR-swizzled LDS (lgkm
// counter) so the in-loop compute never issues vmcnt-ordered loads that
// would drain the prefetch queue.
__global__ __launch_bounds__(256, 3) void edge_mlp_pipe(
    const short* __restrict__ xbf, const int* __restrict__ ei,
    const float* __restrict__ ea,
    const short* __restrict__ w1aTg, const float* __restrict__ b1a,
    const short* __restrict__ w1bTg, const float* __restrict__ b1b,
    short* __restrict__ summedh, float* __restrict__ counts,
    int E, int NT, int NWV)
{
    __shared__ alignas(16) char  lsW[32768];        // w1a swz (16K) + w1b padded swz (16K)
    __shared__ alignas(16) short lsH[4 * 16 * 72];  // wave-private repack slices

    const int t = threadIdx.x;
    const int lane = t & 63;
    const int w = t >> 6;
    const int q = lane >> 4;
    const int m = lane & 15;
    short* hw = lsH + w * (16 * 72);
    const int* hwi = (const int*)hw;

    // ---- stage swizzled weights into LDS (byte ^= ((row&15)<<4), 256-B rows)
    {
        const int4* g1 = (const int4*)w1aTg;        // 16 KB = 1024 chunks
        for (int c = t; c < 1024; c += 256) {
            int b = c << 4;
            *(int4*)(lsW + (b ^ (((b >> 8) & 15) << 4))) = g1[c];
        }
        const int4* g2 = (const int4*)w1bTg;        // 8 KB packed -> 256-B padded rows
        for (int c = t; c < 512; c += 256) {
            int b = c << 4;
            int pb = ((b >> 7) << 8) | (b & 127);
            *(int4*)(lsW + 16384 + (pb ^ (((pb >> 8) & 15) << 4))) = g2[c];
        }
    }
    float ba[4], bb[4];
#pragma unroll
    for (int nt = 0; nt < 4; ++nt) { ba[nt] = b1a[nt * 16 + m]; bb[nt] = b1b[nt * 16 + m]; }
    __syncthreads();   // lsW shared by all 4 waves; only block-wide sync in kernel

    long pA = (long)blockIdx.x * 4 + w;
    if (pA >= NT) return;

    // ---- prologue: rows+gathers for tile A, rows for tile B
    long eA = pA * 16 + m;
    long ecA = eA < E ? eA : (long)(E - 1);
    int rA = ei[ecA];
    int dA = ei[E + ecA];

    long pB = pA + NWV;
    long ecB = 0;
    int rB = 0, dB = 0;
    if (pB < NT) {
        long eB = pB * 16 + m;
        ecB = eB < E ? eB : (long)(E - 1);
        rB = ei[ecB];
        dB = ei[E + ecB];
    }

    bf16x8 xa0A, xa1A; float4 e0A, e1A, e2A, e3A;
    {
        const short* xr = xbf + (long)rA * DF;
        xa0A = *(const bf16x8*)&xr[q * 8];
        xa1A = *(const bf16x8*)&xr[32 + q * 8];
        const float4* er = (const float4*)(ea + ecA * DF);
        e0A = er[q * 2]; e1A = er[q * 2 + 1];
        e2A = er[8 + q * 2]; e3A = er[8 + q * 2 + 1];
    }

    for (;;) {
        // ---- prefetch set B (stays in flight through the whole compute below)
        bf16x8 xa0B, xa1B; float4 e0B, e1B, e2B, e3B;
        if (pB < NT) {
            const short* xr = xbf + (long)rB * DF;
            xa0B = *(const bf16x8*)&xr[q * 8];
            xa1B = *(const bf16x8*)&xr[32 + q * 8];
            const float4* er = (const float4*)(ea + ecB * DF);
            e0B = er[q * 2]; e1B = er[q * 2 + 1];
            e2B = er[8 + q * 2]; e3B = er[8 + q * 2 + 1];
        }
        // ---- rows for tile C (2 iterations ahead)
        long pC = pB + NWV;
        long ecC = 0;
        int rC = 0, dC = 0;
        if (pC < NT) {
            long eC = pC * 16 + m;
            ecC = eC < E ? eC : (long)(E - 1);
            rC = ei[ecC];
            dC = ei[E + ecC];
        }

        // ---- compute tile A (waits only on A-set; B-set stays outstanding)
        const long base = pA * 16;
        if (q == 0 && eA < E) unsafeAtomicAdd(&counts[dA], 1.0f);

        bf16x8 afr[4];
        afr[0] = xa0A; afr[1] = xa1A;
        afr[2] = cvt8(e0A, e1A); afr[3] = cvt8(e2A, e3A);

        f32x4 acc[4];
#pragma unroll
        for (int nt = 0; nt < 4; ++nt) {
            f32x4 v = {ba[nt], ba[nt], ba[nt], ba[nt]};
            acc[nt] = v;
#pragma unroll
            for (int ks = 0; ks < 4; ++ks) {
                const bf16x8 wf = *(const bf16x8*)(lsW +
                    (((nt * 16 + m) << 8) + ((((ks) << 6) | (q << 4)) ^ (m << 4))));
                acc[nt] = __builtin_amdgcn_mfma_f32_16x16x32_bf16(afr[ks], wf, acc[nt], 0, 0, 0);
            }
        }

        // relu, D-layout -> A-layout via wave-private LDS
#pragma unroll
        for (int nt = 0; nt < 4; ++nt)
#pragma unroll
            for (int r = 0; r < 4; ++r) {
                float v = acc[nt][r] > 0.f ? acc[nt][r] : 0.f;
                hw[(q * 4 + r) * 72 + nt * 16 + m] = f2bf(v);
            }
        wave_lds_sync();

        bf16x8 a2[2];
        a2[0] = *(const bf16x8*)&hw[m * 72 + q * 8];
        a2[1] = *(const bf16x8*)&hw[m * 72 + 32 + q * 8];

        f32x4 acd[4];
#pragma unroll
        for (int nt = 0; nt < 4; ++nt) {
            f32x4 v = {bb[nt], bb[nt], bb[nt], bb[nt]};
            acd[nt] = v;
#pragma unroll
            for (int ks = 0; ks < 2; ++ks) {
                const bf16x8 wf = *(const bf16x8*)(lsW + 16384 +
                    (((nt * 16 + m) << 8) + ((((ks) << 6) | (q << 4)) ^ (m << 4))));
                acd[nt] = __builtin_amdgcn_mfma_f32_16x16x32_bf16(a2[ks], wf, acd[nt], 0, 0, 0);
            }
        }
        wave_lds_sync();

#pragma unroll
        for (int nt = 0; nt < 4; ++nt)
#pragma unroll
            for (int r = 0; r < 4; ++r)
                hw[(q * 4 + r) * 72 + nt * 16 + m] = f2bf(acd[nt][r]);
        wave_lds_sync();

        // packed scatter; dst via shfl from the pipelined dA (no reloads)
        const int pp = lane & 31;
#pragma unroll
        for (int i = 0; i < 8; ++i) {
            int r2 = (lane >> 5) + 2 * i;
            long eg = base + r2;
            if (eg < E) {
                int dst = __shfl(dA, r2);
                pk_add(&summedh[(long)dst * DF + 2 * pp], hwi[r2 * 36 + pp]);
            }
        }
        wave_lds_sync();   // scatter's LDS reads drained before next overwrite

        // ---- rotate pipeline
        if (pB >= NT) break;
        pA = pB; eA = pA * 16 + m; rA = rB; dA = dB;
        xa0A = xa0B; xa1A = xa1B;
        e0A = e0B; e1A = e1B; e2A = e2B; e3A = e3B;
        pB = pC; ecB = ecC; rB = rC; dB = dC;
    }
}

// Node MLP: input = concat(xbf, summedh/max(counts,1)); 2 tiles (32 nodes)/wave.
__global__ __launch_bounds__(256, 4) void node_mlp(
    const short* __restrict__ xbf, const short* __restrict__ summedh,
    const float* __restrict__ counts,
    const short* __restrict__ w2aT, const float* __restrict__ b2a,
    const short* __restrict__ w2bT, const float* __restrict__ b2b,
    float* __restrict__ out, int NN)
{
    __shared__ alignas(16) short lsH[4 * 2 * 16 * 72];

    const int t = threadIdx.x;
    const int lane = t & 63;
    const int w = t >> 6;
    const int q = lane >> 4;
    const int m = lane & 15;
    const long base = ((long)blockIdx.x * 4 + w) * 32;

    const long n0 = base + m;
    const long n1 = base + 16 + m;
    const long nc0 = n0 < NN ? n0 : (long)(NN - 1);
    const long nc1 = n1 < NN ? n1 : (long)(NN - 1);

    bf16x8 afr0[4], afr1[4];
    afr0[0] = *(const bf16x8*)&xbf[nc0 * DF + q * 8];
    afr0[1] = *(const bf16x8*)&xbf[nc0 * DF + 32 + q * 8];
    afr1[0] = *(const bf16x8*)&xbf[nc1 * DF + q * 8];
    afr1[1] = *(const bf16x8*)&xbf[nc1 * DF + 32 + q * 8];
    bf16x8 s00 = *(const bf16x8*)&summedh[nc0 * DF + q * 8];
    bf16x8 s01 = *(const bf16x8*)&summedh[nc0 * DF + 32 + q * 8];
    bf16x8 s10 = *(const bf16x8*)&summedh[nc1 * DF + q * 8];
    bf16x8 s11 = *(const bf16x8*)&summedh[nc1 * DF + 32 + q * 8];
    float c0 = counts[nc0];
    float c1 = counts[nc1];
    c0 = c0 > 1.f ? c0 : 1.f;
    c1 = c1 > 1.f ? c1 : 1.f;
    const float inv0 = 1.f / c0;
    const float inv1 = 1.f / c1;

#pragma unroll
    for (int i = 0; i < 8; ++i) {
        afr0[2][i] = f2bf(bf2f((unsigned short)s00[i]) * inv0);
        afr0[3][i] = f2bf(bf2f((unsigned short)s01[i]) * inv0);
        afr1[2][i] = f2bf(bf2f((unsigned short)s10[i]) * inv1);
        afr1[3][i] = f2bf(bf2f((unsigned short)s11[i]) * inv1);
    }

    f32x4 acc0[4], acc1[4];
#pragma unroll
    for (int nt = 0; nt < 4; ++nt) {
        float b = b2a[nt * 16 + m];
        f32x4 v = {b, b, b, b};
        acc0[nt] = v; acc1[nt] = v;
#pragma unroll
        for (int ks = 0; ks < 4; ++ks) {
            bf16x8 wf = *(const bf16x8*)&w2aT[(nt * 16 + m) * 128 + ks * 32 + q * 8];
            acc0[nt] = __builtin_amdgcn_mfma_f32_16x16x32_bf16(afr0[ks], wf, acc0[nt], 0, 0, 0);
            acc1[nt] = __builtin_amdgcn_mfma_f32_16x16x32_bf16(afr1[ks], wf, acc1[nt], 0, 0, 0);
        }
    }

    short* hw0 = lsH + w * (2 * 16 * 72);
    short* hw1 = hw0 + 16 * 72;
#pragma unroll
    for (int nt = 0; nt < 4; ++nt)
#pragma unroll
        for (int r = 0; r < 4; ++r) {
            float v0 = acc0[nt][r] > 0.f ? acc0[nt][r] : 0.f;
            float v1 = acc1[nt][r] > 0.f ? acc1[nt][r] : 0.f;
            hw0[(q * 4 + r) * 72 + nt * 16 + m] = f2bf(v0);
            hw1[(q * 4 + r) * 72 + nt * 16 + m] = f2bf(v1);
        }
    wave_lds_sync();

    bf16x8 a20[2], a21[2];
    a20[0] = *(const bf16x8*)&hw0[m * 72 + q * 8];
    a20[1] = *(const bf16x8*)&hw0[m * 72 + 32 + q * 8];
    a21[0] = *(const bf16x8*)&hw1[m * 72 + q * 8];
    a21[1] = *(const bf16x8*)&hw1[m * 72 + 32 + q * 8];

    f32x4 acd0[4], acd1[4];
#pragma unroll
    for (int nt = 0; nt < 4; ++nt) {
        float b = b2b[nt * 16 + m];
        f32x4 v = {b, b, b, b};
        acd0[nt] = v; acd1[nt] = v;
#pragma unroll
        for (int ks = 0; ks < 2; ++ks) {
            bf16x8 wf = *(const bf16x8*)&w2bT[(nt * 16 + m) * 64 + ks * 32 + q * 8];
            acd0[nt] = __builtin_amdgcn_mfma_f32_16x16x32_bf16(a20[ks], wf, acd0[nt], 0, 0, 0);
            acd1[nt] = __builtin_amdgcn_mfma_f32_16x16x32_bf16(a21[ks], wf, acd1[nt], 0, 0, 0);
        }
    }

#pragma unroll
    for (int r = 0; r < 4; ++r) {
        long o0 = base + q * 4 + r;
        long o1 = base + 16 + q * 4 + r;
        if (o0 < NN) {
#pragma unroll
            for (int nt = 0; nt < 4; ++nt)
                out[o0 * DF + nt * 16 + m] = acd0[nt][r];
        }
        if (o1 < NN) {
#pragma unroll
            for (int nt = 0; nt < 4; ++nt)
                out[o1 * DF + nt * 16 + m] = acd1[nt][r];
        }
    }
}

// ------------------------------ launcher -------------------------------------

extern "C" void kernel_launch(void* const* d_in, const int* in_sizes, int n_in,
                              void* d_out, int out_size, void* d_ws, size_t ws_size,
                              hipStream_t stream) {
    const float* x   = (const float*)d_in[0];
    const int*   ei  = (const int*)d_in[1];
    const float* ea  = (const float*)d_in[2];
    const float* w1a = (const float*)d_in[5];
    const float* b1a = (const float*)d_in[6];
    const float* w1b = (const float*)d_in[7];
    const float* b1b = (const float*)d_in[8];
    const float* w2a = (const float*)d_in[9];
    const float* b2a = (const float*)d_in[10];
    const float* w2b = (const float*)d_in[11];
    const float* b2b = (const float*)d_in[12];

    const int NN = in_sizes[0] / DF;   // 50000
    const int E  = in_sizes[2] / DF;   // 800000

    char* wsb = (char*)d_ws;
    float* counts  = (float*)wsb;                    // 200 KB (pad to 256 KB)
    short* w1aT    = (short*)(wsb + 262144);         // 16 KB
    short* w1bT    = (short*)(wsb + 278528);         // 8 KB
    short* w2aT    = (short*)(wsb + 286720);         // 16 KB
    short* w2bT    = (short*)(wsb + 303104);         // 8 KB
    short* summedh = (short*)(wsb + 311296);         // 6.4 MB bf16 accumulator
    short* xbf     = (short*)(wsb + 6815744);        // 6.4 MB bf16 x

    hipMemsetAsync(counts, 0, (size_t)NN * sizeof(float), stream);
    hipMemsetAsync(summedh, 0, (size_t)NN * DF * sizeof(short), stream);
    prep_weights<<<96, 256, 0, stream>>>(w1a, w1b, w2a, w2b, w1aT, w1bT, w2aT, w2bT);
    int n8 = NN * DF / 8;
    conv_x<<<(n8 + 255) / 256, 256, 0, stream>>>(x, xbf, n8);

    const int EBLOCKS = 768;                         // 3 blocks/CU resident
    const int NT = (E + 15) / 16;
    edge_mlp_pipe<<<EBLOCKS, 256, 0, stream>>>(xbf, ei, ea, w1aT, b1a, w1bT, b1b,
                                               summedh, counts, E, NT, EBLOCKS * 4);

    int nwaves = (NN + 31) / 32;
    int nblocks = (nwaves + 3) / 4;
    node_mlp<<<nblocks, 256, 0, stream>>>(xbf, summedh, counts, w2aT, b2a, w2bT, b2b,
                                          (float*)d_out, NN);
}

// Round 7
// 396.494 us; speedup vs baseline: 1.4271x; 1.0099x over previous
//
#include <hip/hip_runtime.h>

#define DF 64

typedef __attribute__((ext_vector_type(8))) short bf16x8;
typedef __attribute__((ext_vector_type(2))) short v2s;
typedef __attribute__((ext_vector_type(4))) float f32x4;

__device__ __forceinline__ short f2bf(float f) {
    union { float f; unsigned u; } v; v.f = f;
    unsigned u = v.u;
    u += 0x7FFFu + ((u >> 16) & 1u);   // RNE
    return (short)(u >> 16);
}

__device__ __forceinline__ float bf2f(unsigned s) {
    union { unsigned u; float f; } v; v.u = s << 16;
    return v.f;
}

__device__ __forceinline__ bf16x8 cvt8(float4 a, float4 b) {
    bf16x8 r;
    r[0] = f2bf(a.x); r[1] = f2bf(a.y); r[2] = f2bf(a.z); r[3] = f2bf(a.w);
    r[4] = f2bf(b.x); r[5] = f2bf(b.y); r[6] = f2bf(b.z); r[7] = f2bf(b.w);
    return r;
}

// Intra-wave LDS sync (rule #18). sched_barrier(0) also pins the software
// pipeline: prefetch loads issued before the fence cannot sink below it.
__device__ __forceinline__ void wave_lds_sync() {
    asm volatile("s_waitcnt lgkmcnt(0)" ::: "memory");
    __builtin_amdgcn_sched_barrier(0);
}

// packed bf16x2 atomic add (fire-and-forget)
__device__ __forceinline__ void pk_add(short* addr, int val) {
#if __has_builtin(__builtin_amdgcn_global_atomic_fadd_v2bf16)
    __builtin_amdgcn_global_atomic_fadd_v2bf16(
        (__attribute__((address_space(1))) v2s*)addr, *(v2s*)&val);
#else
    unsigned* a = (unsigned*)addr;
    unsigned old = *a, assumed;
    do {
        assumed = old;
        float lo = bf2f(assumed & 0xffffu) + bf2f((unsigned)val & 0xffffu);
        float hi = bf2f(assumed >> 16)     + bf2f((unsigned)val >> 16);
        unsigned nv = (unsigned)(unsigned short)f2bf(lo) |
                      ((unsigned)(unsigned short)f2bf(hi) << 16);
        old = atomicCAS(a, assumed, nv);
    } while (old != assumed);
#endif
}

// Transpose + convert the 4 weight matrices to bf16 [n][k] (B^T) once per launch.
__global__ __launch_bounds__(256) void prep_weights(
    const float* __restrict__ w1a, const float* __restrict__ w1b,
    const float* __restrict__ w2a, const float* __restrict__ w2b,
    short* __restrict__ w1aT, short* __restrict__ w1bT,
    short* __restrict__ w2aT, short* __restrict__ w2bT)
{
    int gid = blockIdx.x * 256 + threadIdx.x;   // 24576 total
    if (gid < 8192) {
        int k = gid >> 6, n = gid & 63;
        w1aT[n * 128 + k] = f2bf(w1a[gid]);
    } else if (gid < 12288) {
        int g = gid - 8192; int k = g >> 6, n = g & 63;
        w1bT[n * 64 + k] = f2bf(w1b[g]);
    } else if (gid < 20480) {
        int g = gid - 12288; int k = g >> 6, n = g & 63;
        w2aT[n * 128 + k] = f2bf(w2a[g]);
    } else if (gid < 24576) {
        int g = gid - 20480; int k = g >> 6, n = g & 63;
        w2bT[n * 64 + k] = f2bf(w2b[g]);
    }
}

// x -> bf16 (RNE, identical values to the previous per-edge conversion).
__global__ __launch_bounds__(256) void conv_x(
    const float* __restrict__ x, short* __restrict__ xbf, int n8)
{
    int gid = blockIdx.x * 256 + threadIdx.x;
    if (gid < n8) {
        const float4* p = (const float4*)x + (long)gid * 2;
        float4 a = p[0], b = p[1];
        ((bf16x8*)xbf)[gid] = cvt8(a, b);
    }
}

// Edge MLP + packed-bf16 scatter-add. Persistent grid-stride waves, 1-deep
// software pipeline. Steady-state body is STRAIGHT-LINE (prefetch indices
// clamped, not branched) so VMEM issue counts are static and the compiler
// can emit counted s_waitcnt vmcnt(N) — the A-set drains without waiting
// for the newer scatter atomics. Weights in XOR-swizzled LDS (lgkm counter)
// keep the in-loop compute off the vmcnt path.
__global__ __launch_bounds__(256, 4) void edge_mlp_pipe(
    const short* __restrict__ xbf, const int* __restrict__ ei,
    const float* __restrict__ ea,
    const short* __restrict__ w1aTg, const float* __restrict__ b1a,
    const short* __restrict__ w1bTg, const float* __restrict__ b1b,
    short* __restrict__ summedh, float* __restrict__ counts,
    int E, int NT, int NWV)
{
    __shared__ alignas(16) char  lsW[24576];        // w1a swz 16K + w1b swz 8K
    __shared__ alignas(16) short lsH[4 * 16 * 72];  // wave-private repack slices

    const int t = threadIdx.x;
    const int lane = t & 63;
    const int w = t >> 6;
    const int q = lane >> 4;
    const int m = lane & 15;
    short* hw = lsH + w * (16 * 72);
    const int* hwi = (const int*)hw;

    // ---- stage swizzled weights into LDS
    {
        // w1a: 256-B rows, byte ^= ((row&15)<<4)
        const int4* g1 = (const int4*)w1aTg;        // 16 KB = 1024 chunks
        for (int c = t; c < 1024; c += 256) {
            int b = c << 4;
            *(int4*)(lsW + (b ^ (((b >> 8) & 15) << 4))) = g1[c];
        }
        // w1b: 128-B rows packed, byte ^= ((row&7)<<4)  (2-way conflicts = free)
        const int4* g2 = (const int4*)w1bTg;        // 8 KB = 512 chunks
        for (int c = t; c < 512; c += 256) {
            int b = c << 4;
            *(int4*)(lsW + 16384 + (b ^ (((b >> 7) & 7) << 4))) = g2[c];
        }
    }
    float ba[4], bb[4];
#pragma unroll
    for (int nt = 0; nt < 4; ++nt) { ba[nt] = b1a[nt * 16 + m]; bb[nt] = b1b[nt * 16 + m]; }
    __syncthreads();   // lsW shared by all 4 waves; only block-wide sync in kernel

    long pA = (long)blockIdx.x * 4 + w;
    if (pA >= NT) return;

    // ---- prologue: rows+gathers for tile A, rows for tile B (clamped)
    long eA = pA * 16 + m;
    long ecA = eA < E ? eA : (long)(E - 1);
    int rA = ei[ecA];
    int dA = ei[E + ecA];

    long pB = pA + NWV;
    long eB = pB * 16 + m;
    long ecB = eB < E ? eB : (long)(E - 1);
    int rB = ei[ecB];
    int dB = ei[E + ecB];

    bf16x8 xa0A, xa1A; float4 e0A, e1A, e2A, e3A;
    {
        const short* xr = xbf + (long)rA * DF;
        xa0A = *(const bf16x8*)&xr[q * 8];
        xa1A = *(const bf16x8*)&xr[32 + q * 8];
        const float4* er = (const float4*)(ea + ecA * DF);
        e0A = er[q * 2]; e1A = er[q * 2 + 1];
        e2A = er[8 + q * 2]; e3A = er[8 + q * 2 + 1];
    }

    for (;;) {
        // ---- prefetch set B (clamped addresses; stays in flight through compute)
        bf16x8 xa0B, xa1B; float4 e0B, e1B, e2B, e3B;
        {
            const short* xr = xbf + (long)rB * DF;
            xa0B = *(const bf16x8*)&xr[q * 8];
            xa1B = *(const bf16x8*)&xr[32 + q * 8];
            const float4* er = (const float4*)(ea + ecB * DF);
            e0B = er[q * 2]; e1B = er[q * 2 + 1];
            e2B = er[8 + q * 2]; e3B = er[8 + q * 2 + 1];
        }
        // ---- rows for tile C (2 iterations ahead, clamped)
        long pC = pB + NWV;
        long eC = pC * 16 + m;
        long ecC = eC < E ? eC : (long)(E - 1);
        int rC = ei[ecC];
        int dC = ei[E + ecC];

        // ---- compute tile A (counted wait drains only the A-set)
        const long base = pA * 16;
        if (q == 0 && eA < E) unsafeAtomicAdd(&counts[dA], 1.0f);

        bf16x8 afr[4];
        afr[0] = xa0A; afr[1] = xa1A;
        afr[2] = cvt8(e0A, e1A); afr[3] = cvt8(e2A, e3A);

        f32x4 acc[4];
#pragma unroll
        for (int nt = 0; nt < 4; ++nt) {
            f32x4 v = {ba[nt], ba[nt], ba[nt], ba[nt]};
            acc[nt] = v;
#pragma unroll
            for (int ks = 0; ks < 4; ++ks) {
                const bf16x8 wf = *(const bf16x8*)(lsW +
                    (((nt * 16 + m) << 8) + ((((ks) << 6) | (q << 4)) ^ (m << 4))));
                acc[nt] = __builtin_amdgcn_mfma_f32_16x16x32_bf16(afr[ks], wf, acc[nt], 0, 0, 0);
            }
        }

        // relu, D-layout -> A-layout via wave-private LDS
#pragma unroll
        for (int nt = 0; nt < 4; ++nt)
#pragma unroll
            for (int r = 0; r < 4; ++r) {
                float v = acc[nt][r] > 0.f ? acc[nt][r] : 0.f;
                hw[(q * 4 + r) * 72 + nt * 16 + m] = f2bf(v);
            }
        wave_lds_sync();

        bf16x8 a2[2];
        a2[0] = *(const bf16x8*)&hw[m * 72 + q * 8];
        a2[1] = *(const bf16x8*)&hw[m * 72 + 32 + q * 8];

        f32x4 acd[4];
#pragma unroll
        for (int nt = 0; nt < 4; ++nt) {
            f32x4 v = {bb[nt], bb[nt], bb[nt], bb[nt]};
            acd[nt] = v;
#pragma unroll
            for (int ks = 0; ks < 2; ++ks) {
                const bf16x8 wf = *(const bf16x8*)(lsW + 16384 +
                    (((nt * 16 + m) << 7) + ((((ks) << 6) | (q << 4)) ^ ((m & 7) << 4))));
                acd[nt] = __builtin_amdgcn_mfma_f32_16x16x32_bf16(a2[ks], wf, acd[nt], 0, 0, 0);
            }
        }
        wave_lds_sync();

#pragma unroll
        for (int nt = 0; nt < 4; ++nt)
#pragma unroll
            for (int r = 0; r < 4; ++r)
                hw[(q * 4 + r) * 72 + nt * 16 + m] = f2bf(acd[nt][r]);
        wave_lds_sync();

        // packed scatter; dst via shfl from the pipelined dA (no reloads)
        const int pp = lane & 31;
#pragma unroll
        for (int i = 0; i < 8; ++i) {
            int r2 = (lane >> 5) + 2 * i;
            long eg = base + r2;
            if (eg < E) {
                int dst = __shfl(dA, r2);
                pk_add(&summedh[(long)dst * DF + 2 * pp], hwi[r2 * 36 + pp]);
            }
        }
        wave_lds_sync();   // scatter's LDS reads drained before next overwrite

        // ---- rotate pipeline
        if (pB >= NT) break;
        pA = pB; eA = pA * 16 + m; rA = rB; dA = dB;
        xa0A = xa0B; xa1A = xa1B;
        e0A = e0B; e1A = e1B; e2A = e2B; e3A = e3B;
        pB = pC; ecB = ecC; rB = rC; dB = dC;
    }
}

// Node MLP: input = concat(xbf, summedh/max(counts,1)); 2 tiles (32 nodes)/wave.
__global__ __launch_bounds__(256, 4) void node_mlp(
    const short* __restrict__ xbf, const short* __restrict__ summedh,
    const float* __restrict__ counts,
    const short* __restrict__ w2aT, const float* __restrict__ b2a,
    const short* __restrict__ w2bT, const float* __restrict__ b2b,
    float* __restrict__ out, int NN)
{
    __shared__ alignas(16) short lsH[4 * 2 * 16 * 72];

    const int t = threadIdx.x;
    const int lane = t & 63;
    const int w = t >> 6;
    const int q = lane >> 4;
    const int m = lane & 15;
    const long base = ((long)blockIdx.x * 4 + w) * 32;

    const long n0 = base + m;
    const long n1 = base + 16 + m;
    const long nc0 = n0 < NN ? n0 : (long)(NN - 1);
    const long nc1 = n1 < NN ? n1 : (long)(NN - 1);

    bf16x8 afr0[4], afr1[4];
    afr0[0] = *(const bf16x8*)&xbf[nc0 * DF + q * 8];
    afr0[1] = *(const bf16x8*)&xbf[nc0 * DF + 32 + q * 8];
    afr1[0] = *(const bf16x8*)&xbf[nc1 * DF + q * 8];
    afr1[1] = *(const bf16x8*)&xbf[nc1 * DF + 32 + q * 8];
    bf16x8 s00 = *(const bf16x8*)&summedh[nc0 * DF + q * 8];
    bf16x8 s01 = *(const bf16x8*)&summedh[nc0 * DF + 32 + q * 8];
    bf16x8 s10 = *(const bf16x8*)&summedh[nc1 * DF + q * 8];
    bf16x8 s11 = *(const bf16x8*)&summedh[nc1 * DF + 32 + q * 8];
    float c0 = counts[nc0];
    float c1 = counts[nc1];
    c0 = c0 > 1.f ? c0 : 1.f;
    c1 = c1 > 1.f ? c1 : 1.f;
    const float inv0 = 1.f / c0;
    const float inv1 = 1.f / c1;

#pragma unroll
    for (int i = 0; i < 8; ++i) {
        afr0[2][i] = f2bf(bf2f((unsigned short)s00[i]) * inv0);
        afr0[3][i] = f2bf(bf2f((unsigned short)s01[i]) * inv0);
        afr1[2][i] = f2bf(bf2f((unsigned short)s10[i]) * inv1);
        afr1[3][i] = f2bf(bf2f((unsigned short)s11[i]) * inv1);
    }

    f32x4 acc0[4], acc1[4];
#pragma unroll
    for (int nt = 0; nt < 4; ++nt) {
        float b = b2a[nt * 16 + m];
        f32x4 v = {b, b, b, b};
        acc0[nt] = v; acc1[nt] = v;
#pragma unroll
        for (int ks = 0; ks < 4; ++ks) {
            bf16x8 wf = *(const bf16x8*)&w2aT[(nt * 16 + m) * 128 + ks * 32 + q * 8];
            acc0[nt] = __builtin_amdgcn_mfma_f32_16x16x32_bf16(afr0[ks], wf, acc0[nt], 0, 0, 0);
            acc1[nt] = __builtin_amdgcn_mfma_f32_16x16x32_bf16(afr1[ks], wf, acc1[nt], 0, 0, 0);
        }
    }

    short* hw0 = lsH + w * (2 * 16 * 72);
    short* hw1 = hw0 + 16 * 72;
#pragma unroll
    for (int nt = 0; nt < 4; ++nt)
#pragma unroll
        for (int r = 0; r < 4; ++r) {
            float v0 = acc0[nt][r] > 0.f ? acc0[nt][r] : 0.f;
            float v1 = acc1[nt][r] > 0.f ? acc1[nt][r] : 0.f;
            hw0[(q * 4 + r) * 72 + nt * 16 + m] = f2bf(v0);
            hw1[(q * 4 + r) * 72 + nt * 16 + m] = f2bf(v1);
        }
    wave_lds_sync();

    bf16x8 a20[2], a21[2];
    a20[0] = *(const bf16x8*)&hw0[m * 72 + q * 8];
    a20[1] = *(const bf16x8*)&hw0[m * 72 + 32 + q * 8];
    a21[0] = *(const bf16x8*)&hw1[m * 72 + q * 8];
    a21[1] = *(const bf16x8*)&hw1[m * 72 + 32 + q * 8];

    f32x4 acd0[4], acd1[4];
#pragma unroll
    for (int nt = 0; nt < 4; ++nt) {
        float b = b2b[nt * 16 + m];
        f32x4 v = {b, b, b, b};
        acd0[nt] = v; acd1[nt] = v;
#pragma unroll
        for (int ks = 0; ks < 2; ++ks) {
            bf16x8 wf = *(const bf16x8*)&w2bT[(nt * 16 + m) * 64 + ks * 32 + q * 8];
            acd0[nt] = __builtin_amdgcn_mfma_f32_16x16x32_bf16(a20[ks], wf, acd0[nt], 0, 0, 0);
            acd1[nt] = __builtin_amdgcn_mfma_f32_16x16x32_bf16(a21[ks], wf, acd1[nt], 0, 0, 0);
        }
    }

#pragma unroll
    for (int r = 0; r < 4; ++r) {
        long o0 = base + q * 4 + r;
        long o1 = base + 16 + q * 4 + r;
        if (o0 < NN) {
#pragma unroll
            for (int nt = 0; nt < 4; ++nt)
                out[o0 * DF + nt * 16 + m] = acd0[nt][r];
        }
        if (o1 < NN) {
#pragma unroll
            for (int nt = 0; nt < 4; ++nt)
                out[o1 * DF + nt * 16 + m] = acd1[nt][r];
        }
    }
}

// ------------------------------ launcher -------------------------------------

extern "C" void kernel_launch(void* const* d_in, const int* in_sizes, int n_in,
                              void* d_out, int out_size, void* d_ws, size_t ws_size,
                              hipStream_t stream) {
    const float* x   = (const float*)d_in[0];
    const int*   ei  = (const int*)d_in[1];
    const float* ea  = (const float*)d_in[2];
    const float* w1a = (const float*)d_in[5];
    const float* b1a = (const float*)d_in[6];
    const float* w1b = (const float*)d_in[7];
    const float* b1b = (const float*)d_in[8];
    const float* w2a = (const float*)d_in[9];
    const float* b2a = (const float*)d_in[10];
    const float* w2b = (const float*)d_in[11];
    const float* b2b = (const float*)d_in[12];

    const int NN = in_sizes[0] / DF;   // 50000
    const int E  = in_sizes[2] / DF;   // 800000

    char* wsb = (char*)d_ws;
    float* counts  = (float*)wsb;                    // 200 KB (pad to 256 KB)
    short* w1aT    = (short*)(wsb + 262144);         // 16 KB
    short* w1bT    = (short*)(wsb + 278528);         // 8 KB
    short* w2aT    = (short*)(wsb + 286720);         // 16 KB
    short* w2bT    = (short*)(wsb + 303104);         // 8 KB
    short* summedh = (short*)(wsb + 311296);         // 6.4 MB bf16 accumulator
    short* xbf     = (short*)(wsb + 6815744);        // 6.4 MB bf16 x

    hipMemsetAsync(counts, 0, (size_t)NN * sizeof(float), stream);
    hipMemsetAsync(summedh, 0, (size_t)NN * DF * sizeof(short), stream);
    prep_weights<<<96, 256, 0, stream>>>(w1a, w1b, w2a, w2b, w1aT, w1bT, w2aT, w2bT);
    int n8 = NN * DF / 8;
    conv_x<<<(n8 + 255) / 256, 256, 0, stream>>>(x, xbf, n8);

    const int EBLOCKS = 1024;                        // 4 blocks/CU resident (33.8 KB LDS)
    const int NT = (E + 15) / 16;
    edge_mlp_pipe<<<EBLOCKS, 256, 0, stream>>>(xbf, ei, ea, w1aT, b1a, w1bT, b1b,
                                               summedh, counts, E, NT, EBLOCKS * 4);

    int nwaves = (NN + 31) / 32;
    int nblocks = (nwaves + 3) / 4;
    node_mlp<<<nblocks, 256, 0, stream>>>(xbf, summedh, counts, w2aT, b2a, w2bT, b2b,
                                          (float*)d_out, NN);
}